// Round 9
// baseline (216.488 us; speedup 1.0000x reference)
//
#include <hip/hip_runtime.h>

#define LTAG 64
#define L2E 1.4426950408889634f
#define LN2 0.6931471805599453f

// v_exp_f32: 2^x ; v_log_f32: log2(x)
__device__ __forceinline__ float exp2_fast(float x) { return __builtin_amdgcn_exp2f(x); }
__device__ __forceinline__ float log2_fast(float x) { return __builtin_amdgcn_logf(x); }

__device__ __forceinline__ float readlane_f(float v, int lane) {
    return __int_as_float(__builtin_amdgcn_readlane(__float_as_int(v), lane));
}
// lane crossbar pull: result[lane] = v[abytes[lane] >> 2]
__device__ __forceinline__ float bperm_f(int abytes, float v) {
    return __int_as_float(__builtin_amdgcn_ds_bpermute(abytes, __float_as_int(v)));
}

// One wave (64 lanes) per batch element. lane = next-tag index n.
//
// ROUND-9 = ROUND-8 STRUCTURE with the OOB unroll fixed (the r8 pair-loop
// `d=1; d<32; d+=2` touched er[32]/w[32]/adr[32] — UB -> inf. Now exactly
// 31 bpermutes, d=1..31, parity-split accumulators).
//
// Rotation matvec on the lane crossbar:
//   s[n] = sum_d A[(n+d)&63] * Etr[(n+d)&63][n]
// rot_d = ds_bpermute(A) with STEP-INVARIANT address regs (no readlane —
// ~7cy effective each, r4 fit; no LDS array round-trip — ~250cy, r3/5/6/7;
// no barrier). 31 independent bpermutes issue on the DS pipe and overlap
// with 64 VALU fmacs.
// Upper half via swap identity  rot_{d+32}[n] == rot_d[n^32]:
//   u[m] = sum_{d<32} rot_d[m] * w_d[m],  w_d[m] = Etr[(m+d)&63][m^32] (const)
//   s[n] = s_lo[n] + u[n^32]   (one final bpermute)
//
// Exp-domain recurrence (r2-r7 verified): A[n] = exp2(alpha[n]*L2E - SH),
//   A'[n] = s[n] * g[n],  g[n] = exp2(x_t[n]*L2E + c2[n])
// with Etr[p][n] = exp2(trans[p][n]*L2E - c2[n]), c2[n] = col max.
// Exact power-of-2 rescale every 4 steps (growth <2^19/step, sampled-max
// spread ~2^35; 35+4*19 < 127). Column B (lane 0) fully masked (-10000):
// g[B]==0 exactly -> A[B]==0 throughout; true final value recovered
// analytically (lane-0 Etr column is all-ones after c2 normalization):
//   alpha_T[B] = (log2 s_B + x*L2E + c2_B + SH)*LN2  from the last step.
__global__ __launch_bounds__(64) void crf_forward_kernel(
    const float* __restrict__ X, const float* __restrict__ trans,
    float* __restrict__ out, int T) {
    const int lane = threadIdx.x;
    const int b = blockIdx.x;
    const float* xb = X + (size_t)b * T * LTAG + lane;

    const int swaddr = (lane ^ 32) << 2;  // partner-lane crossbar address

    // ---- precompute rotated transition tables (once) ----
    // er[d][n](lane n) = Etr[(n+d)&63][n], d=0..31
    // w[d][m](lane m)  = Etr[(m+d)&63][m^32]  (upper half, pre-swapped)
    float er[32], w[32];
    float c2 = -3.0e38f;
    {
        float tmp[64];
#pragma unroll
        for (int d = 0; d < 64; ++d) {
            tmp[d] = trans[(((lane + d) & 63) << 6) + lane] * L2E;
            c2 = fmaxf(c2, tmp[d]);  // == column max over p (rotation covers all p)
        }
#pragma unroll
        for (int d = 0; d < 64; ++d) tmp[d] = exp2_fast(tmp[d] - c2);
#pragma unroll
        for (int d = 0; d < 32; ++d) er[d] = tmp[d];
#pragma unroll
        for (int d = 0; d < 32; ++d) w[d] = bperm_f(swaddr, tmp[d + 32]);
    }

    // step-invariant rotation addresses (kept in VGPRs, hoisted out of loop)
    int adr[32];
#pragma unroll
    for (int d = 0; d < 32; ++d) adr[d] = ((lane + d) & 63) << 2;

    // ---- init: alpha = NEG except tag B (lane 0) = 0 ----
    float A = (lane == 0) ? 1.0f : 0.0f;
    float SH = 0.0f;
    float sB = 1.0f, xB = 0.0f, shB = 0.0f;  // lane-0 (tag B) fixup state

    // ---- x prefetch ring, distance 4 ----
    float xr[4];
#pragma unroll
    for (int i = 0; i < 4; ++i) xr[i] = xb[(size_t)i * LTAG];

    for (int t = 0; t < T; t += 4) {
#pragma unroll
        for (int u = 0; u < 4; ++u) {
            const float xcur = xr[u];
            int tpf = t + u + 4;
            tpf = tpf < T ? tpf : T - 1;
            xr[u] = xb[(size_t)tpf * LTAG];

            // off the serial chain: exp2 latency hides under the matvec
            const float g = exp2_fast(fmaf(xcur, L2E, c2));

            // ---- rotation matvec: exactly 31 bpermutes (d=1..31) + d=0 ----
            float s0 = A * er[0];  // d=0: identity rotation
            float u0 = A * w[0];
            float s1 = 0.f, u1 = 0.f;
#pragma unroll
            for (int d = 1; d < 32; ++d) {
                const float r = bperm_f(adr[d], A);
                if (d & 1) {
                    s1 = fmaf(r, er[d], s1);
                    u1 = fmaf(r, w[d], u1);
                } else {
                    s0 = fmaf(r, er[d], s0);
                    u0 = fmaf(r, w[d], u0);
                }
            }
            const float slo = s0 + s1;
            const float uu = u0 + u1;
            const float shi = bperm_f(swaddr, uu);  // u[n^32] = upper-half sum
            const float s = slo + shi;

            sB = s; xB = xcur; shB = SH;  // last-step save for lane-0 fixup
            A = s * g;

            if (u == 3) {
                // ---- wave-uniform EXACT power-of-2 rescale, every 4 steps --
                // samples avoid lane 0 (tag B: exactly 0 in exp domain)
                float mm = fmaxf(readlane_f(A, 2), readlane_f(A, 19));
                mm = fmaxf(mm, readlane_f(A, 28));
                mm = fmaxf(mm, fmaxf(readlane_f(A, 37), readlane_f(A, 53)));
                int eb2 = (__float_as_int(mm) >> 23) & 0xff;  // biased exp
                eb2 = eb2 < 1 ? 1 : eb2;                      // safety clamp
                A *= __int_as_float((254 - eb2) << 23);  // *= 2^(127-eb), exact
                SH += (float)(eb2 - 127);
            }
        }
    }

    float res;
    if (lane == 0) {
        // tag B analytic fixup (see header comment)
        res = (log2_fast(sB) + fmaf(xB, L2E, c2) + shB) * LN2;
    } else {
        res = (log2_fast(A) + SH) * LN2;
    }
    out[b * LTAG + lane] = res;
}

extern "C" void kernel_launch(void* const* d_in, const int* in_sizes, int n_in,
                              void* d_out, int out_size, void* d_ws, size_t ws_size,
                              hipStream_t stream) {
    const float* X = (const float*)d_in[0];
    const float* trans = (const float*)d_in[1];
    float* out = (float*)d_out;

    const int B = out_size / LTAG;           // 256
    const int T = in_sizes[0] / (B * LTAG);  // 512

    crf_forward_kernel<<<B, LTAG, 0, stream>>>(X, trans, out, T);
}